// Round 9
// baseline (1147.545 us; speedup 1.0000x reference)
//
#include <hip/hip_runtime.h>
#include <hip/hip_bf16.h>
#include <cstdint>

#define NNODES 100000
#define NEDGES 1000000
#define HDIM 64
#define ODIM 16
#define NB 8
#define KDIM (HDIM * NB)   // 512
#define DEGB 256           // degree buckets for counting sort

typedef short short8 __attribute__((ext_vector_type(8)));
typedef float f32x4  __attribute__((ext_vector_type(4)));
union FragU { uint4 u; short8 s; };

__device__ __forceinline__ float asf(uint32_t u) { float f; __builtin_memcpy(&f, &u, 4); return f; }
__device__ __forceinline__ uint32_t asu(float f) { uint32_t u; __builtin_memcpy(&u, &f, 4); return u; }
__device__ __forceinline__ uint16_t f2bf(float f) {
    uint32_t x = asu(f);
    return (uint16_t)((x + 0x7FFFu + ((x >> 16) & 1u)) >> 16);
}
__device__ __forceinline__ uint32_t pack2(float lo, float hi) {
    return (uint32_t)f2bf(lo) | ((uint32_t)f2bf(hi) << 16);
}
__device__ __forceinline__ int rot6(int v) { return ((v << 3) | (v >> 3)) & 63; }
__device__ __forceinline__ void fmaC(const float4& cA, const float4& cB, float xs,
                                     float* __restrict__ acc) {
    acc[0] = fmaf(cA.x, xs, acc[0]); acc[1] = fmaf(cA.y, xs, acc[1]);
    acc[2] = fmaf(cA.z, xs, acc[2]); acc[3] = fmaf(cA.w, xs, acc[3]);
    acc[4] = fmaf(cB.x, xs, acc[4]); acc[5] = fmaf(cB.y, xs, acc[5]);
    acc[6] = fmaf(cB.z, xs, acc[6]); acc[7] = fmaf(cB.w, xs, acc[7]);
}

// ---------------------------------------------------------------------------
// generic helpers
// ---------------------------------------------------------------------------
__global__ void zero_kernel(int* __restrict__ p, int n) {
    for (int i = (int)(blockIdx.x * blockDim.x + threadIdx.x); i < n;
         i += (int)(gridDim.x * blockDim.x)) p[i] = 0;
}

__global__ void hist_kernel(const int* __restrict__ dst, int* __restrict__ cnt, int nE) {
    for (int e = (int)(blockIdx.x * blockDim.x + threadIdx.x); e < nE;
         e += (int)(gridDim.x * blockDim.x)) atomicAdd(&cnt[dst[e]], 1);
}

// ---------------------------------------------------------------------------
// degree counting-sort: node -> rank, tiles of 32 consecutive ranks share degree
// ---------------------------------------------------------------------------
__global__ void deghist_kernel(const int* __restrict__ cnt, int* __restrict__ degcount, int n) {
    for (int i = (int)(blockIdx.x * blockDim.x + threadIdx.x); i < n;
         i += (int)(gridDim.x * blockDim.x)) {
        int b = cnt[i]; if (b > DEGB - 1) b = DEGB - 1;
        atomicAdd(&degcount[b], 1);
    }
}

__launch_bounds__(DEGB)
__global__ void degscan_kernel(const int* __restrict__ degcount, int* __restrict__ dcur) {
    __shared__ int sh[DEGB];
    const int t = (int)threadIdx.x;
    int v = degcount[t];
    sh[t] = v;
    __syncthreads();
    for (int off = 1; off < DEGB; off <<= 1) {
        int tmp = (t >= off) ? sh[t - off] : 0;
        __syncthreads();
        sh[t] += tmp;
        __syncthreads();
    }
    dcur[t] = sh[t] - v;   // exclusive base; becomes atomic cursor
}

__global__ void rank_kernel(const int* __restrict__ cnt, int* __restrict__ dcur,
                            int* __restrict__ rank, int* __restrict__ invperm,
                            int* __restrict__ degarr, int n) {
    for (int i = (int)(blockIdx.x * blockDim.x + threadIdx.x); i < n;
         i += (int)(gridDim.x * blockDim.x)) {
        int dg = cnt[i];
        int b = dg > DEGB - 1 ? DEGB - 1 : dg;
        int r = atomicAdd(&dcur[b], 1);
        rank[i]   = r;
        invperm[r] = i;
        degarr[r] = dg;
    }
}

// ---------------------------------------------------------------------------
// scan pipeline over degarr (rank-ordered degrees) -> offs + cursors
// ---------------------------------------------------------------------------
#define SCAN_B 512
__launch_bounds__(SCAN_B)
__global__ void scan_partial_kernel(const int* __restrict__ cnt, int* __restrict__ bsum, int n) {
    __shared__ int sh[SCAN_B];
    int id = (int)(blockIdx.x * SCAN_B + threadIdx.x);
    sh[threadIdx.x] = (id < n) ? cnt[id] : 0;
    __syncthreads();
    for (int off = SCAN_B / 2; off > 0; off >>= 1) {
        if ((int)threadIdx.x < off) sh[threadIdx.x] += sh[threadIdx.x + off];
        __syncthreads();
    }
    if (threadIdx.x == 0) bsum[blockIdx.x] = sh[0];
}

__launch_bounds__(256)
__global__ void scan_base_kernel(const int* __restrict__ bsum, int* __restrict__ bbase,
                                 int* __restrict__ offs, int nblk, int nNodes) {
    __shared__ int sh[256];
    const int t = (int)threadIdx.x;
    int v = (t < nblk) ? bsum[t] : 0;
    sh[t] = v;
    __syncthreads();
    for (int off = 1; off < 256; off <<= 1) {
        int tmp = (t >= off) ? sh[t - off] : 0;
        __syncthreads();
        sh[t] += tmp;
        __syncthreads();
    }
    if (t < nblk) bbase[t] = sh[t] - v;
    if (t == 255) offs[nNodes] = sh[255];
}

__launch_bounds__(SCAN_B)
__global__ void scan_final_kernel(int* __restrict__ cnt, const int* __restrict__ bbase,
                                  int* __restrict__ offs, int n) {
    __shared__ int sh[SCAN_B];
    int id = (int)(blockIdx.x * SCAN_B + threadIdx.x);
    int v = (id < n) ? cnt[id] : 0;
    sh[threadIdx.x] = v;
    __syncthreads();
    for (int off = 1; off < SCAN_B; off <<= 1) {
        int tmp = ((int)threadIdx.x >= off) ? sh[threadIdx.x - off] : 0;
        __syncthreads();
        sh[threadIdx.x] += tmp;
        __syncthreads();
    }
    if (id < n) {
        int excl = sh[threadIdx.x] - v + bbase[blockIdx.x];
        offs[id] = excl;
        cnt[id]  = excl;   // becomes the scatter cursor
    }
}

// scatter edges into rank-space CSR: rec = { rank[src] | et<<20, norm }
__global__ void scatter_kernel(const int* __restrict__ src, const int* __restrict__ dst,
                               const int* __restrict__ et, const float* __restrict__ norm,
                               const int* __restrict__ rank,
                               int* __restrict__ cursor, uint2* __restrict__ rec, int nE) {
    for (int e = (int)(blockIdx.x * blockDim.x + threadIdx.x); e < nE;
         e += (int)(gridDim.x * blockDim.x)) {
        int p = atomicAdd(&cursor[rank[dst[e]]], 1);
        rec[p] = make_uint2((uint32_t)rank[src[e]] | ((uint32_t)et[e] << 20), asu(norm[e]));
    }
}

// cast feats into rank space: x[r][i] = bf16(feats[invperm[r]][i])
__global__ void cast_kernel(const float* __restrict__ in, const int* __restrict__ invperm,
                            uint16_t* __restrict__ out, int n4) {
    const int stride = (int)(gridDim.x * blockDim.x);
    for (int idx = (int)(blockIdx.x * blockDim.x + threadIdx.x); idx < n4; idx += stride) {
        const int r    = idx >> 4;            // 16 float4 per row
        const int col4 = idx & 15;
        float4 v = *reinterpret_cast<const float4*>(in + (size_t)invperm[r] * HDIM + col4 * 4);
        uint2 p;
        p.x = pack2(v.x, v.y);
        p.y = pack2(v.z, v.w);
        reinterpret_cast<uint2*>(out)[idx] = p;
    }
}

// ---------------------------------------------------------------------------
// FUSED layer (rank space): agg (half-wave/node -> LDS G-tile) + MFMA + epilogue.
// LDS chunk swizzle: chunk' = rot6(c8) ^ (m&7) -> agg b128 writes hit all 8
// bank groups (minimal); MFMA reads 2-way (free).
// mfma_f32_16x16x32_bf16: A[m=lane&15][k=(lane>>4)*8+j], B[k][n=lane&15],
// C col=lane&15, row=(lane>>4)*4+reg.
// Hidden layers write xout in rank space (coalesced); final layer scatters
// f32 rows to out[invperm[r]] (64 B full-line writes).
// ---------------------------------------------------------------------------
template <int DOUT, bool RELU, bool F32OUT>
__launch_bounds__(256)
__global__ void fused_layer_kernel(const uint16_t* __restrict__ xin,
                                   const float* __restrict__ coeff,
                                   const int* __restrict__ offs,
                                   const uint2* __restrict__ rec,
                                   const float* __restrict__ bases,
                                   const float* __restrict__ bias,
                                   const int* __restrict__ invperm,
                                   uint16_t* __restrict__ xout,
                                   float* __restrict__ fout,
                                   int nNodes) {
    constexpr int OT = DOUT / 16;       // 4 (hidden) or 1 (out)
    __shared__ __align__(16) uint16_t Gt[32 * KDIM];   // 32 KB

    const int t    = (int)threadIdx.x;
    const int lane = t & 63;
    const int w    = t >> 6;
    const int hw   = t >> 5;
    const int hl   = t & 31;
    const int q    = lane >> 4;
    const int c    = lane & 15;
    const int ot   = (OT == 4) ? w : 0;

    // B fragments (this wave's o-tile) global -> regs: frag kb elem j -> i=kb*4+q, b=j
    FragU bfr[16];
#pragma unroll
    for (int kb = 0; kb < 16; kb++) {
        uint16_t tmp[8];
        const int i = kb * 4 + q;
#pragma unroll
        for (int j = 0; j < 8; j++)
            tmp[j] = f2bf(bases[((size_t)j * HDIM + i) * DOUT + ot * 16 + c]);
        __builtin_memcpy(&bfr[kb], tmp, 16);
    }
    const float bv = bias[ot * 16 + c];

    const int nTiles = (nNodes + 31) / 32;
    for (int tile = blockIdx.x; tile < nTiles; tile += gridDim.x) {
        const int n0 = tile * 32;
        __syncthreads();

        // ---- aggregation: half-wave hw -> nodes m = 4*hw .. 4*hw+3 (ranks)
        for (int r = 0; r < 4; r++) {
            const int m = hw * 4 + r;
            const int d = n0 + m;
            float accL[NB] = {0.f, 0.f, 0.f, 0.f, 0.f, 0.f, 0.f, 0.f};  // i=2hl
            float accH[NB] = {0.f, 0.f, 0.f, 0.f, 0.f, 0.f, 0.f, 0.f};  // i=2hl+1
            if (d < nNodes) {
                const int j0 = offs[d], j1 = offs[d + 1];
                int j = j0;
                for (; j + 4 <= j1; j += 4) {
                    const uint2 r0 = rec[j];
                    const uint2 r1 = rec[j + 1];
                    const uint2 r2 = rec[j + 2];
                    const uint2 r3 = rec[j + 3];
                    const uint32_t w0 = *reinterpret_cast<const uint32_t*>(
                        xin + (size_t)(r0.x & 0xFFFFFu) * HDIM + 2 * hl);
                    const uint32_t w1 = *reinterpret_cast<const uint32_t*>(
                        xin + (size_t)(r1.x & 0xFFFFFu) * HDIM + 2 * hl);
                    const uint32_t w2 = *reinterpret_cast<const uint32_t*>(
                        xin + (size_t)(r2.x & 0xFFFFFu) * HDIM + 2 * hl);
                    const uint32_t w3 = *reinterpret_cast<const uint32_t*>(
                        xin + (size_t)(r3.x & 0xFFFFFu) * HDIM + 2 * hl);
                    {
                        const float4 cA = *reinterpret_cast<const float4*>(coeff + (r0.x >> 20) * NB);
                        const float4 cB = *reinterpret_cast<const float4*>(coeff + (r0.x >> 20) * NB + 4);
                        const float nm = asf(r0.y);
                        fmaC(cA, cB, asf(w0 << 16) * nm, accL);
                        fmaC(cA, cB, asf(w0 & 0xFFFF0000u) * nm, accH);
                    }
                    {
                        const float4 cA = *reinterpret_cast<const float4*>(coeff + (r1.x >> 20) * NB);
                        const float4 cB = *reinterpret_cast<const float4*>(coeff + (r1.x >> 20) * NB + 4);
                        const float nm = asf(r1.y);
                        fmaC(cA, cB, asf(w1 << 16) * nm, accL);
                        fmaC(cA, cB, asf(w1 & 0xFFFF0000u) * nm, accH);
                    }
                    {
                        const float4 cA = *reinterpret_cast<const float4*>(coeff + (r2.x >> 20) * NB);
                        const float4 cB = *reinterpret_cast<const float4*>(coeff + (r2.x >> 20) * NB + 4);
                        const float nm = asf(r2.y);
                        fmaC(cA, cB, asf(w2 << 16) * nm, accL);
                        fmaC(cA, cB, asf(w2 & 0xFFFF0000u) * nm, accH);
                    }
                    {
                        const float4 cA = *reinterpret_cast<const float4*>(coeff + (r3.x >> 20) * NB);
                        const float4 cB = *reinterpret_cast<const float4*>(coeff + (r3.x >> 20) * NB + 4);
                        const float nm = asf(r3.y);
                        fmaC(cA, cB, asf(w3 << 16) * nm, accL);
                        fmaC(cA, cB, asf(w3 & 0xFFFF0000u) * nm, accH);
                    }
                }
                for (; j < j1; j++) {
                    const uint2 r0 = rec[j];
                    const uint32_t w0 = *reinterpret_cast<const uint32_t*>(
                        xin + (size_t)(r0.x & 0xFFFFFu) * HDIM + 2 * hl);
                    const float4 cA = *reinterpret_cast<const float4*>(coeff + (r0.x >> 20) * NB);
                    const float4 cB = *reinterpret_cast<const float4*>(coeff + (r0.x >> 20) * NB + 4);
                    const float nm = asf(r0.y);
                    fmaC(cA, cB, asf(w0 << 16) * nm, accL);
                    fmaC(cA, cB, asf(w0 & 0xFFFF0000u) * nm, accH);
                }
            }
            uint4 lo, hi;
            lo.x = pack2(accL[0], accL[1]); lo.y = pack2(accL[2], accL[3]);
            lo.z = pack2(accL[4], accL[5]); lo.w = pack2(accL[6], accL[7]);
            hi.x = pack2(accH[0], accH[1]); hi.y = pack2(accH[2], accH[3]);
            hi.z = pack2(accH[4], accH[5]); hi.w = pack2(accH[6], accH[7]);
            const int sw = m & 7;
            *reinterpret_cast<uint4*>(Gt + m * KDIM + ((rot6(2 * hl)     ^ sw) << 3)) = lo;
            *reinterpret_cast<uint4*>(Gt + m * KDIM + ((rot6(2 * hl + 1) ^ sw) << 3)) = hi;
        }
        __syncthreads();

        // ---- MFMA + epilogue
        if (OT == 4) {
            const int m0 = c, m1 = 16 + c;
            f32x4 acc0 = {0.f, 0.f, 0.f, 0.f};
            f32x4 acc1 = {0.f, 0.f, 0.f, 0.f};
#pragma unroll
            for (int kb = 0; kb < 16; kb++) {
                const int ch = rot6(kb * 4 + q);
                FragU a0, a1;
                a0.u = *reinterpret_cast<const uint4*>(Gt + m0 * KDIM + ((ch ^ (m0 & 7)) << 3));
                a1.u = *reinterpret_cast<const uint4*>(Gt + m1 * KDIM + ((ch ^ (m1 & 7)) << 3));
                acc0 = __builtin_amdgcn_mfma_f32_16x16x32_bf16(a0.s, bfr[kb].s, acc0, 0, 0, 0);
                acc1 = __builtin_amdgcn_mfma_f32_16x16x32_bf16(a1.s, bfr[kb].s, acc1, 0, 0, 0);
            }
#pragma unroll
            for (int r2 = 0; r2 < 4; r2++) {
                int node = n0 + q * 4 + r2;
                if (node < nNodes) {
                    float v = acc0[r2] + bv;
                    if (RELU) v = fmaxf(v, 0.f);
                    xout[(size_t)node * DOUT + ot * 16 + c] = f2bf(v);
                }
                node = n0 + 16 + q * 4 + r2;
                if (node < nNodes) {
                    float v = acc1[r2] + bv;
                    if (RELU) v = fmaxf(v, 0.f);
                    xout[(size_t)node * DOUT + ot * 16 + c] = f2bf(v);
                }
            }
        } else {
            if (w < 2) {
                const int m0 = w * 16 + c;
                f32x4 acc = {0.f, 0.f, 0.f, 0.f};
#pragma unroll
                for (int kb = 0; kb < 16; kb++) {
                    const int ch = rot6(kb * 4 + q);
                    FragU a0;
                    a0.u = *reinterpret_cast<const uint4*>(Gt + m0 * KDIM + ((ch ^ (m0 & 7)) << 3));
                    acc = __builtin_amdgcn_mfma_f32_16x16x32_bf16(a0.s, bfr[kb].s, acc, 0, 0, 0);
                }
#pragma unroll
                for (int r2 = 0; r2 < 4; r2++) {
                    const int node = n0 + w * 16 + q * 4 + r2;
                    if (node < nNodes)
                        fout[(size_t)invperm[node] * DOUT + c] = acc[r2] + bv;
                }
            }
        }
    }
}

extern "C" void kernel_launch(void* const* d_in, const int* in_sizes, int n_in,
                              void* d_out, int out_size, void* d_ws, size_t ws_size,
                              hipStream_t stream) {
    const float* feats  = (const float*)d_in[0];
    const float* coeff0 = (const float*)d_in[1];
    const float* bases0 = (const float*)d_in[2];
    const float* bias0  = (const float*)d_in[3];
    const float* coeff1 = (const float*)d_in[4];
    const float* bases1 = (const float*)d_in[5];
    const float* bias1  = (const float*)d_in[6];
    const float* coeff2 = (const float*)d_in[7];
    const float* bases2 = (const float*)d_in[8];
    const float* bias2  = (const float*)d_in[9];
    const int*   src    = (const int*)d_in[10];
    const int*   dst    = (const int*)d_in[11];
    const int*   etype  = (const int*)d_in[12];
    const float* norm   = (const float*)d_in[13];
    float* out = (float*)d_out;

    char* base = (char*)d_ws;
    uint16_t* x0 = (uint16_t*)base;                        // 12.8 MB
    uint16_t* x1 = (uint16_t*)(base + 12800000);           // 12.8 MB
    const size_t OFF_OFFS   = 25600000;
    const size_t OFF_CNT    = OFF_OFFS   + 400016;         // orig-node degree counts
    const size_t OFF_RANK   = OFF_CNT    + 400016;
    const size_t OFF_INVP   = OFF_RANK   + 400016;
    const size_t OFF_DEGARR = OFF_INVP   + 400016;         // rank-ordered degrees / cursors
    const size_t OFF_BSUM   = OFF_DEGARR + 400016;
    const size_t OFF_BBASE  = OFF_BSUM   + 1024;
    const size_t OFF_DEGC   = OFF_BBASE  + 1024;           // degree histogram
    const size_t OFF_DCUR   = OFF_DEGC   + 1024;           // degree bucket cursors
    const size_t OFF_REC    = OFF_DCUR   + 1024;           // 8 MB
    int*   offs   = (int*)(base + OFF_OFFS);
    int*   cnt    = (int*)(base + OFF_CNT);
    int*   rank   = (int*)(base + OFF_RANK);
    int*   invp   = (int*)(base + OFF_INVP);
    int*   degarr = (int*)(base + OFF_DEGARR);
    int*   bsum   = (int*)(base + OFF_BSUM);
    int*   bbase  = (int*)(base + OFF_BBASE);
    int*   degc   = (int*)(base + OFF_DEGC);
    int*   dcur   = (int*)(base + OFF_DCUR);
    uint2* rec    = (uint2*)(base + OFF_REC);

    const int nblk   = (NNODES + SCAN_B - 1) / SCAN_B;   // 196 <= 256
    const int nTiles = (NNODES + 31) / 32;               // 3125

    // ---- degree histogram + counting sort (node -> rank)
    hipLaunchKernelGGL(zero_kernel, dim3(256), dim3(256), 0, stream, cnt, NNODES);
    hipLaunchKernelGGL(zero_kernel, dim3(1), dim3(256), 0, stream, degc, DEGB);
    hipLaunchKernelGGL(hist_kernel, dim3(2048), dim3(256), 0, stream, dst, cnt, NEDGES);
    hipLaunchKernelGGL(deghist_kernel, dim3(391), dim3(256), 0, stream, cnt, degc, NNODES);
    hipLaunchKernelGGL(degscan_kernel, dim3(1), dim3(DEGB), 0, stream, degc, dcur);
    hipLaunchKernelGGL(rank_kernel, dim3(391), dim3(256), 0, stream,
                       cnt, dcur, rank, invp, degarr, NNODES);

    // ---- rank-space CSR offsets + edge scatter
    hipLaunchKernelGGL(scan_partial_kernel, dim3(nblk), dim3(SCAN_B), 0, stream, degarr, bsum, NNODES);
    hipLaunchKernelGGL(scan_base_kernel, dim3(1), dim3(256), 0, stream, bsum, bbase, offs, nblk, NNODES);
    hipLaunchKernelGGL(scan_final_kernel, dim3(nblk), dim3(SCAN_B), 0, stream, degarr, bbase, offs, NNODES);
    hipLaunchKernelGGL(scatter_kernel, dim3(2048), dim3(256), 0, stream,
                       src, dst, etype, norm, rank, degarr, rec, NEDGES);

    // ---- x0 = bf16(feats) permuted into rank space
    hipLaunchKernelGGL(cast_kernel, dim3(2048), dim3(256), 0, stream,
                       feats, invp, x0, NNODES * HDIM / 4);

    // ---- 3 fused layers (rank space; exact-tile grid)
    hipLaunchKernelGGL((fused_layer_kernel<64, true, false>), dim3(nTiles), dim3(256), 0, stream,
                       x0, coeff0, offs, rec, bases0, bias0, invp, x1, (float*)nullptr, NNODES);
    hipLaunchKernelGGL((fused_layer_kernel<64, true, false>), dim3(nTiles), dim3(256), 0, stream,
                       x1, coeff1, offs, rec, bases1, bias1, invp, x0, (float*)nullptr, NNODES);
    hipLaunchKernelGGL((fused_layer_kernel<16, false, true>), dim3(nTiles), dim3(256), 0, stream,
                       x0, coeff2, offs, rec, bases2, bias2, invp, (uint16_t*)nullptr, out, NNODES);
}

// Round 10
// 568.966 us; speedup vs baseline: 2.0169x; 2.0169x over previous
//
#include <hip/hip_runtime.h>
#include <hip/hip_bf16.h>
#include <cstdint>

#define NNODES 100000
#define NEDGES 1000000
#define HDIM 64
#define ODIM 16
#define NB 8
#define KDIM (HDIM * NB)   // 512
#define DEGB 256           // degree buckets for counting sort
#define NBLKR ((NNODES + 255) / 256)   // 391 node-blocks for the sort

typedef short short8 __attribute__((ext_vector_type(8)));
typedef float f32x4  __attribute__((ext_vector_type(4)));
union FragU { uint4 u; short8 s; };

__device__ __forceinline__ float asf(uint32_t u) { float f; __builtin_memcpy(&f, &u, 4); return f; }
__device__ __forceinline__ uint32_t asu(float f) { uint32_t u; __builtin_memcpy(&u, &f, 4); return u; }
__device__ __forceinline__ uint16_t f2bf(float f) {
    uint32_t x = asu(f);
    return (uint16_t)((x + 0x7FFFu + ((x >> 16) & 1u)) >> 16);
}
__device__ __forceinline__ uint32_t pack2(float lo, float hi) {
    return (uint32_t)f2bf(lo) | ((uint32_t)f2bf(hi) << 16);
}
__device__ __forceinline__ int rot6(int v) { return ((v << 3) | (v >> 3)) & 63; }
__device__ __forceinline__ void fmaC(const float4& cA, const float4& cB, float xs,
                                     float* __restrict__ acc) {
    acc[0] = fmaf(cA.x, xs, acc[0]); acc[1] = fmaf(cA.y, xs, acc[1]);
    acc[2] = fmaf(cA.z, xs, acc[2]); acc[3] = fmaf(cA.w, xs, acc[3]);
    acc[4] = fmaf(cB.x, xs, acc[4]); acc[5] = fmaf(cB.y, xs, acc[5]);
    acc[6] = fmaf(cB.z, xs, acc[6]); acc[7] = fmaf(cB.w, xs, acc[7]);
}

// ---------------------------------------------------------------------------
// generic helpers
// ---------------------------------------------------------------------------
__global__ void zero_kernel(int* __restrict__ p, int n) {
    for (int i = (int)(blockIdx.x * blockDim.x + threadIdx.x); i < n;
         i += (int)(gridDim.x * blockDim.x)) p[i] = 0;
}

__global__ void hist_kernel(const int* __restrict__ dst, int* __restrict__ cnt, int nE) {
    for (int e = (int)(blockIdx.x * blockDim.x + threadIdx.x); e < nE;
         e += (int)(gridDim.x * blockDim.x)) atomicAdd(&cnt[dst[e]], 1);
}

// ---------------------------------------------------------------------------
// contention-free counting sort: node -> rank (ranks ordered by degree)
// ---------------------------------------------------------------------------
// Stage A: per-block LDS histogram -> blockhist[block][bucket]
__launch_bounds__(256)
__global__ void blockhist_kernel(const int* __restrict__ cnt,
                                 int* __restrict__ blockhist, int n) {
    __shared__ int lh[DEGB];
    const int t = (int)threadIdx.x;
    lh[t] = 0;
    __syncthreads();
    const int i = (int)blockIdx.x * 256 + t;
    if (i < n) {
        int b = cnt[i]; if (b > DEGB - 1) b = DEGB - 1;
        atomicAdd(&lh[b], 1);
    }
    __syncthreads();
    blockhist[(size_t)blockIdx.x * DEGB + t] = lh[t];
}

// Stage B: per-bucket exclusive scan over blocks; bucket totals out
__launch_bounds__(512)
__global__ void colscan_kernel(int* __restrict__ blockhist, int* __restrict__ btot) {
    __shared__ int sh[512];
    const int bucket = (int)blockIdx.x;
    const int t = (int)threadIdx.x;
    int v = (t < NBLKR) ? blockhist[(size_t)t * DEGB + bucket] : 0;
    sh[t] = v;
    __syncthreads();
    for (int off = 1; off < 512; off <<= 1) {
        int tmp = (t >= off) ? sh[t - off] : 0;
        __syncthreads();
        sh[t] += tmp;
        __syncthreads();
    }
    if (t < NBLKR) blockhist[(size_t)t * DEGB + bucket] = sh[t] - v;  // exclusive
    if (t == 511) btot[bucket] = sh[511];
}

// Stage B2: exclusive scan over 256 bucket totals -> degstart
__launch_bounds__(DEGB)
__global__ void degscan_kernel(const int* __restrict__ btot, int* __restrict__ dstart) {
    __shared__ int sh[DEGB];
    const int t = (int)threadIdx.x;
    int v = btot[t];
    sh[t] = v;
    __syncthreads();
    for (int off = 1; off < DEGB; off <<= 1) {
        int tmp = (t >= off) ? sh[t - off] : 0;
        __syncthreads();
        sh[t] += tmp;
        __syncthreads();
    }
    dstart[t] = sh[t] - v;
}

// Stage C: LDS re-histogram with returned local offset -> final rank
__launch_bounds__(256)
__global__ void rank_assign_kernel(const int* __restrict__ cnt,
                                   const int* __restrict__ blockhist,
                                   const int* __restrict__ dstart,
                                   int* __restrict__ rank, int* __restrict__ invperm,
                                   int* __restrict__ degarr, int n) {
    __shared__ int lh[DEGB];
    const int t = (int)threadIdx.x;
    lh[t] = 0;
    __syncthreads();
    const int i = (int)blockIdx.x * 256 + t;
    int b = 0, local = 0, dg = 0;
    if (i < n) {
        dg = cnt[i];
        b = dg > DEGB - 1 ? DEGB - 1 : dg;
        local = atomicAdd(&lh[b], 1);
    }
    __syncthreads();
    if (i < n) {
        const int r = dstart[b] + blockhist[(size_t)blockIdx.x * DEGB + b] + local;
        rank[i]    = r;
        invperm[r] = i;
        degarr[r]  = dg;
    }
}

// ---------------------------------------------------------------------------
// scan pipeline over degarr (rank-ordered degrees) -> offs + cursors
// ---------------------------------------------------------------------------
#define SCAN_B 512
__launch_bounds__(SCAN_B)
__global__ void scan_partial_kernel(const int* __restrict__ cnt, int* __restrict__ bsum, int n) {
    __shared__ int sh[SCAN_B];
    int id = (int)(blockIdx.x * SCAN_B + threadIdx.x);
    sh[threadIdx.x] = (id < n) ? cnt[id] : 0;
    __syncthreads();
    for (int off = SCAN_B / 2; off > 0; off >>= 1) {
        if ((int)threadIdx.x < off) sh[threadIdx.x] += sh[threadIdx.x + off];
        __syncthreads();
    }
    if (threadIdx.x == 0) bsum[blockIdx.x] = sh[0];
}

__launch_bounds__(256)
__global__ void scan_base_kernel(const int* __restrict__ bsum, int* __restrict__ bbase,
                                 int* __restrict__ offs, int nblk, int nNodes) {
    __shared__ int sh[256];
    const int t = (int)threadIdx.x;
    int v = (t < nblk) ? bsum[t] : 0;
    sh[t] = v;
    __syncthreads();
    for (int off = 1; off < 256; off <<= 1) {
        int tmp = (t >= off) ? sh[t - off] : 0;
        __syncthreads();
        sh[t] += tmp;
        __syncthreads();
    }
    if (t < nblk) bbase[t] = sh[t] - v;
    if (t == 255) offs[nNodes] = sh[255];
}

__launch_bounds__(SCAN_B)
__global__ void scan_final_kernel(int* __restrict__ cnt, const int* __restrict__ bbase,
                                  int* __restrict__ offs, int n) {
    __shared__ int sh[SCAN_B];
    int id = (int)(blockIdx.x * SCAN_B + threadIdx.x);
    int v = (id < n) ? cnt[id] : 0;
    sh[threadIdx.x] = v;
    __syncthreads();
    for (int off = 1; off < SCAN_B; off <<= 1) {
        int tmp = ((int)threadIdx.x >= off) ? sh[threadIdx.x - off] : 0;
        __syncthreads();
        sh[threadIdx.x] += tmp;
        __syncthreads();
    }
    if (id < n) {
        int excl = sh[threadIdx.x] - v + bbase[blockIdx.x];
        offs[id] = excl;
        cnt[id]  = excl;   // becomes the scatter cursor
    }
}

// scatter edges into rank-space CSR: rec = { rank[src] | et<<20, norm }
__global__ void scatter_kernel(const int* __restrict__ src, const int* __restrict__ dst,
                               const int* __restrict__ et, const float* __restrict__ norm,
                               const int* __restrict__ rank,
                               int* __restrict__ cursor, uint2* __restrict__ rec, int nE) {
    for (int e = (int)(blockIdx.x * blockDim.x + threadIdx.x); e < nE;
         e += (int)(gridDim.x * blockDim.x)) {
        int p = atomicAdd(&cursor[rank[dst[e]]], 1);
        rec[p] = make_uint2((uint32_t)rank[src[e]] | ((uint32_t)et[e] << 20), asu(norm[e]));
    }
}

// cast feats into rank space: x[r][i] = bf16(feats[invperm[r]][i])
__global__ void cast_kernel(const float* __restrict__ in, const int* __restrict__ invperm,
                            uint16_t* __restrict__ out, int n4) {
    const int stride = (int)(gridDim.x * blockDim.x);
    for (int idx = (int)(blockIdx.x * blockDim.x + threadIdx.x); idx < n4; idx += stride) {
        const int r    = idx >> 4;            // 16 float4 per row
        const int col4 = idx & 15;
        float4 v = *reinterpret_cast<const float4*>(in + (size_t)invperm[r] * HDIM + col4 * 4);
        uint2 p;
        p.x = pack2(v.x, v.y);
        p.y = pack2(v.z, v.w);
        reinterpret_cast<uint2*>(out)[idx] = p;
    }
}

// ---------------------------------------------------------------------------
// FUSED layer (rank space): agg (half-wave/node -> LDS G-tile) + MFMA + epilogue.
// LDS chunk swizzle: chunk' = rot6(c8) ^ (m&7). mfma_f32_16x16x32_bf16:
// A[m=lane&15][k=(lane>>4)*8+j], B[k][n=lane&15], C col=lane&15, row=q*4+reg.
// ---------------------------------------------------------------------------
template <int DOUT, bool RELU, bool F32OUT>
__launch_bounds__(256)
__global__ void fused_layer_kernel(const uint16_t* __restrict__ xin,
                                   const float* __restrict__ coeff,
                                   const int* __restrict__ offs,
                                   const uint2* __restrict__ rec,
                                   const float* __restrict__ bases,
                                   const float* __restrict__ bias,
                                   const int* __restrict__ invperm,
                                   uint16_t* __restrict__ xout,
                                   float* __restrict__ fout,
                                   int nNodes) {
    constexpr int OT = DOUT / 16;       // 4 (hidden) or 1 (out)
    __shared__ __align__(16) uint16_t Gt[32 * KDIM];   // 32 KB

    const int t    = (int)threadIdx.x;
    const int lane = t & 63;
    const int w    = t >> 6;
    const int hw   = t >> 5;
    const int hl   = t & 31;
    const int q    = lane >> 4;
    const int c    = lane & 15;
    const int ot   = (OT == 4) ? w : 0;

    FragU bfr[16];
#pragma unroll
    for (int kb = 0; kb < 16; kb++) {
        uint16_t tmp[8];
        const int i = kb * 4 + q;
#pragma unroll
        for (int j = 0; j < 8; j++)
            tmp[j] = f2bf(bases[((size_t)j * HDIM + i) * DOUT + ot * 16 + c]);
        __builtin_memcpy(&bfr[kb], tmp, 16);
    }
    const float bv = bias[ot * 16 + c];

    const int nTiles = (nNodes + 31) / 32;
    for (int tile = blockIdx.x; tile < nTiles; tile += gridDim.x) {
        const int n0 = tile * 32;
        __syncthreads();

        for (int r = 0; r < 4; r++) {
            const int m = hw * 4 + r;
            const int d = n0 + m;
            float accL[NB] = {0.f, 0.f, 0.f, 0.f, 0.f, 0.f, 0.f, 0.f};  // i=2hl
            float accH[NB] = {0.f, 0.f, 0.f, 0.f, 0.f, 0.f, 0.f, 0.f};  // i=2hl+1
            if (d < nNodes) {
                const int j0 = offs[d], j1 = offs[d + 1];
                int j = j0;
                for (; j + 4 <= j1; j += 4) {
                    const uint2 r0 = rec[j];
                    const uint2 r1 = rec[j + 1];
                    const uint2 r2 = rec[j + 2];
                    const uint2 r3 = rec[j + 3];
                    const uint32_t w0 = *reinterpret_cast<const uint32_t*>(
                        xin + (size_t)(r0.x & 0xFFFFFu) * HDIM + 2 * hl);
                    const uint32_t w1 = *reinterpret_cast<const uint32_t*>(
                        xin + (size_t)(r1.x & 0xFFFFFu) * HDIM + 2 * hl);
                    const uint32_t w2 = *reinterpret_cast<const uint32_t*>(
                        xin + (size_t)(r2.x & 0xFFFFFu) * HDIM + 2 * hl);
                    const uint32_t w3 = *reinterpret_cast<const uint32_t*>(
                        xin + (size_t)(r3.x & 0xFFFFFu) * HDIM + 2 * hl);
                    {
                        const float4 cA = *reinterpret_cast<const float4*>(coeff + (r0.x >> 20) * NB);
                        const float4 cB = *reinterpret_cast<const float4*>(coeff + (r0.x >> 20) * NB + 4);
                        const float nm = asf(r0.y);
                        fmaC(cA, cB, asf(w0 << 16) * nm, accL);
                        fmaC(cA, cB, asf(w0 & 0xFFFF0000u) * nm, accH);
                    }
                    {
                        const float4 cA = *reinterpret_cast<const float4*>(coeff + (r1.x >> 20) * NB);
                        const float4 cB = *reinterpret_cast<const float4*>(coeff + (r1.x >> 20) * NB + 4);
                        const float nm = asf(r1.y);
                        fmaC(cA, cB, asf(w1 << 16) * nm, accL);
                        fmaC(cA, cB, asf(w1 & 0xFFFF0000u) * nm, accH);
                    }
                    {
                        const float4 cA = *reinterpret_cast<const float4*>(coeff + (r2.x >> 20) * NB);
                        const float4 cB = *reinterpret_cast<const float4*>(coeff + (r2.x >> 20) * NB + 4);
                        const float nm = asf(r2.y);
                        fmaC(cA, cB, asf(w2 << 16) * nm, accL);
                        fmaC(cA, cB, asf(w2 & 0xFFFF0000u) * nm, accH);
                    }
                    {
                        const float4 cA = *reinterpret_cast<const float4*>(coeff + (r3.x >> 20) * NB);
                        const float4 cB = *reinterpret_cast<const float4*>(coeff + (r3.x >> 20) * NB + 4);
                        const float nm = asf(r3.y);
                        fmaC(cA, cB, asf(w3 << 16) * nm, accL);
                        fmaC(cA, cB, asf(w3 & 0xFFFF0000u) * nm, accH);
                    }
                }
                for (; j < j1; j++) {
                    const uint2 r0 = rec[j];
                    const uint32_t w0 = *reinterpret_cast<const uint32_t*>(
                        xin + (size_t)(r0.x & 0xFFFFFu) * HDIM + 2 * hl);
                    const float4 cA = *reinterpret_cast<const float4*>(coeff + (r0.x >> 20) * NB);
                    const float4 cB = *reinterpret_cast<const float4*>(coeff + (r0.x >> 20) * NB + 4);
                    const float nm = asf(r0.y);
                    fmaC(cA, cB, asf(w0 << 16) * nm, accL);
                    fmaC(cA, cB, asf(w0 & 0xFFFF0000u) * nm, accH);
                }
            }
            uint4 lo, hi;
            lo.x = pack2(accL[0], accL[1]); lo.y = pack2(accL[2], accL[3]);
            lo.z = pack2(accL[4], accL[5]); lo.w = pack2(accL[6], accL[7]);
            hi.x = pack2(accH[0], accH[1]); hi.y = pack2(accH[2], accH[3]);
            hi.z = pack2(accH[4], accH[5]); hi.w = pack2(accH[6], accH[7]);
            const int sw = m & 7;
            *reinterpret_cast<uint4*>(Gt + m * KDIM + ((rot6(2 * hl)     ^ sw) << 3)) = lo;
            *reinterpret_cast<uint4*>(Gt + m * KDIM + ((rot6(2 * hl + 1) ^ sw) << 3)) = hi;
        }
        __syncthreads();

        if (OT == 4) {
            const int m0 = c, m1 = 16 + c;
            f32x4 acc0 = {0.f, 0.f, 0.f, 0.f};
            f32x4 acc1 = {0.f, 0.f, 0.f, 0.f};
#pragma unroll
            for (int kb = 0; kb < 16; kb++) {
                const int ch = rot6(kb * 4 + q);
                FragU a0, a1;
                a0.u = *reinterpret_cast<const uint4*>(Gt + m0 * KDIM + ((ch ^ (m0 & 7)) << 3));
                a1.u = *reinterpret_cast<const uint4*>(Gt + m1 * KDIM + ((ch ^ (m1 & 7)) << 3));
                acc0 = __builtin_amdgcn_mfma_f32_16x16x32_bf16(a0.s, bfr[kb].s, acc0, 0, 0, 0);
                acc1 = __builtin_amdgcn_mfma_f32_16x16x32_bf16(a1.s, bfr[kb].s, acc1, 0, 0, 0);
            }
#pragma unroll
            for (int r2 = 0; r2 < 4; r2++) {
                int node = n0 + q * 4 + r2;
                if (node < nNodes) {
                    float v = acc0[r2] + bv;
                    if (RELU) v = fmaxf(v, 0.f);
                    xout[(size_t)node * DOUT + ot * 16 + c] = f2bf(v);
                }
                node = n0 + 16 + q * 4 + r2;
                if (node < nNodes) {
                    float v = acc1[r2] + bv;
                    if (RELU) v = fmaxf(v, 0.f);
                    xout[(size_t)node * DOUT + ot * 16 + c] = f2bf(v);
                }
            }
        } else {
            if (w < 2) {
                const int m0 = w * 16 + c;
                f32x4 acc = {0.f, 0.f, 0.f, 0.f};
#pragma unroll
                for (int kb = 0; kb < 16; kb++) {
                    const int ch = rot6(kb * 4 + q);
                    FragU a0;
                    a0.u = *reinterpret_cast<const uint4*>(Gt + m0 * KDIM + ((ch ^ (m0 & 7)) << 3));
                    acc = __builtin_amdgcn_mfma_f32_16x16x32_bf16(a0.s, bfr[kb].s, acc, 0, 0, 0);
                }
#pragma unroll
                for (int r2 = 0; r2 < 4; r2++) {
                    const int node = n0 + w * 16 + q * 4 + r2;
                    if (node < nNodes)
                        fout[(size_t)invperm[node] * DOUT + c] = acc[r2] + bv;
                }
            }
        }
    }
}

extern "C" void kernel_launch(void* const* d_in, const int* in_sizes, int n_in,
                              void* d_out, int out_size, void* d_ws, size_t ws_size,
                              hipStream_t stream) {
    const float* feats  = (const float*)d_in[0];
    const float* coeff0 = (const float*)d_in[1];
    const float* bases0 = (const float*)d_in[2];
    const float* bias0  = (const float*)d_in[3];
    const float* coeff1 = (const float*)d_in[4];
    const float* bases1 = (const float*)d_in[5];
    const float* bias1  = (const float*)d_in[6];
    const float* coeff2 = (const float*)d_in[7];
    const float* bases2 = (const float*)d_in[8];
    const float* bias2  = (const float*)d_in[9];
    const int*   src    = (const int*)d_in[10];
    const int*   dst    = (const int*)d_in[11];
    const int*   etype  = (const int*)d_in[12];
    const float* norm   = (const float*)d_in[13];
    float* out = (float*)d_out;

    char* base = (char*)d_ws;
    uint16_t* x0 = (uint16_t*)base;                        // 12.8 MB
    uint16_t* x1 = (uint16_t*)(base + 12800000);           // 12.8 MB
    const size_t OFF_OFFS   = 25600000;
    const size_t OFF_CNT    = OFF_OFFS   + 400016;
    const size_t OFF_RANK   = OFF_CNT    + 400016;
    const size_t OFF_INVP   = OFF_RANK   + 400016;
    const size_t OFF_DEGARR = OFF_INVP   + 400016;
    const size_t OFF_BSUM   = OFF_DEGARR + 400016;
    const size_t OFF_BBASE  = OFF_BSUM   + 1024;
    const size_t OFF_BH     = OFF_BBASE  + 1024;           // blockhist 391*256*4
    const size_t OFF_BTOT   = OFF_BH     + 400640;
    const size_t OFF_DSTART = OFF_BTOT   + 1024;
    const size_t OFF_REC    = OFF_DSTART + 1024;           // 8 MB
    int*   offs   = (int*)(base + OFF_OFFS);
    int*   cnt    = (int*)(base + OFF_CNT);
    int*   rank   = (int*)(base + OFF_RANK);
    int*   invp   = (int*)(base + OFF_INVP);
    int*   degarr = (int*)(base + OFF_DEGARR);
    int*   bsum   = (int*)(base + OFF_BSUM);
    int*   bbase  = (int*)(base + OFF_BBASE);
    int*   bh     = (int*)(base + OFF_BH);
    int*   btot   = (int*)(base + OFF_BTOT);
    int*   dstart = (int*)(base + OFF_DSTART);
    uint2* rec    = (uint2*)(base + OFF_REC);

    const int nblk   = (NNODES + SCAN_B - 1) / SCAN_B;   // 196 <= 256
    const int nTiles = (NNODES + 31) / 32;               // 3125

    // ---- degree histogram
    hipLaunchKernelGGL(zero_kernel, dim3(256), dim3(256), 0, stream, cnt, NNODES);
    hipLaunchKernelGGL(hist_kernel, dim3(2048), dim3(256), 0, stream, dst, cnt, NEDGES);

    // ---- contention-free counting sort (node -> rank)
    hipLaunchKernelGGL(blockhist_kernel, dim3(NBLKR), dim3(256), 0, stream, cnt, bh, NNODES);
    hipLaunchKernelGGL(colscan_kernel, dim3(DEGB), dim3(512), 0, stream, bh, btot);
    hipLaunchKernelGGL(degscan_kernel, dim3(1), dim3(DEGB), 0, stream, btot, dstart);
    hipLaunchKernelGGL(rank_assign_kernel, dim3(NBLKR), dim3(256), 0, stream,
                       cnt, bh, dstart, rank, invp, degarr, NNODES);

    // ---- rank-space CSR offsets + edge scatter
    hipLaunchKernelGGL(scan_partial_kernel, dim3(nblk), dim3(SCAN_B), 0, stream, degarr, bsum, NNODES);
    hipLaunchKernelGGL(scan_base_kernel, dim3(1), dim3(256), 0, stream, bsum, bbase, offs, nblk, NNODES);
    hipLaunchKernelGGL(scan_final_kernel, dim3(nblk), dim3(SCAN_B), 0, stream, degarr, bbase, offs, NNODES);
    hipLaunchKernelGGL(scatter_kernel, dim3(2048), dim3(256), 0, stream,
                       src, dst, etype, norm, rank, degarr, rec, NEDGES);

    // ---- x0 = bf16(feats) permuted into rank space
    hipLaunchKernelGGL(cast_kernel, dim3(2048), dim3(256), 0, stream,
                       feats, invp, x0, NNODES * HDIM / 4);

    // ---- 3 fused layers (rank space; exact-tile grid)
    hipLaunchKernelGGL((fused_layer_kernel<64, true, false>), dim3(nTiles), dim3(256), 0, stream,
                       x0, coeff0, offs, rec, bases0, bias0, invp, x1, (float*)nullptr, NNODES);
    hipLaunchKernelGGL((fused_layer_kernel<64, true, false>), dim3(nTiles), dim3(256), 0, stream,
                       x1, coeff1, offs, rec, bases1, bias1, invp, x0, (float*)nullptr, NNODES);
    hipLaunchKernelGGL((fused_layer_kernel<16, false, true>), dim3(nTiles), dim3(256), 0, stream,
                       x0, coeff2, offs, rec, bases2, bias2, invp, (uint16_t*)nullptr, out, NNODES);
}